// Round 1
// baseline (512.795 us; speedup 1.0000x reference)
//
#include <hip/hip_runtime.h>

#define HB  20
#define DD  40
#define BPW 3              // batches per wave (3 x 20 lanes = 60 of 64)
#define WAVES 4            // waves per block (256 threads)
#define BPB (BPW*WAVES)    // 12 batches per block

__device__ __forceinline__ float fast_tanh(float x){
    // tanh(x) = 1 - 2/(exp(2x)+1); exact at +-inf, ~1e-7 rel error
    float e = __expf(2.0f*x);
    return 1.0f - 2.0f*__builtin_amdgcn_rcpf(e + 1.0f);
}

__global__ __launch_bounds__(256, 4)
void ende_kernel(const float* __restrict__ src,
                 const float* __restrict__ w1,
                 const float* __restrict__ w2,
                 const float* __restrict__ w3g,
                 const float* __restrict__ w4g,
                 float* __restrict__ dout,
                 int NB)
{
    // weights staged as (w1,w2) and (w3,w4) float2 pairs, row-padded to 21
    __shared__ float2 w12[HB*21];
    __shared__ float2 w34[HB*21];
    __shared__ float  xs [WAVES][BPW][DD];
    __shared__ float  s2s[WAVES][BPW][HB];
    __shared__ float2 aps[WAVES][BPW][HB];   // (a1, a2)
    __shared__ float2 bps[WAVES][BPW][HB];   // (b1, b2)

    const int t    = threadIdx.x;
    const int wv   = t >> 6;
    const int lane = t & 63;
    const bool act = lane < (BPW*HB);
    const int sub  = lane / HB;          // which batch within the wave
    const int j    = lane % HB;          // owned column
    const int batch0 = blockIdx.x * BPB + wv * BPW;
    const int b    = batch0 + sub;
    const bool valid = act && (b < NB);

    // ---- stage weights to LDS (block-wide) ----
    for (int q = t; q < HB*HB; q += 256){
        int i = q / HB, m = q % HB;
        w12[i*21+m] = make_float2(w1[q],  w2[q]);
        w34[i*21+m] = make_float2(w3g[q], w4g[q]);
    }
    // ---- stage x for this wave's 3 batches ----
    {
        int base = batch0 * DD;
        int lim  = NB * DD;
        for (int l = lane; l < BPW*DD; l += 64){
            int g = base + l;
            if (g < lim) (&xs[wv][0][0])[l] = src[g];
        }
    }
    __syncthreads();

    float e2 = 0.f, s2 = 0.f, e4 = 0.f, t1 = 0.f;

    // ---- stage 1a: f1, f2, e2, s2, a1, a2 ----
    if (act){
        float acc1 = 0.f, acc2 = 0.f;
        #pragma unroll
        for (int m = 0; m < HB; m++){
            float2 w = w12[j*21+m];
            float  p = xs[wv][sub][m];          // p1[m], broadcast per batch
            acc1 = fmaf(p, w.x, acc1);
            acc2 = fmaf(p, w.y, acc2);
        }
        float f1 = fast_tanh(acc1);
        float f2 = fast_tanh(acc2);
        e2 = __expf(f2);
        float p2  = xs[wv][sub][HB+j];
        float p2e = p2 * e2;
        s2 = p2e + f1;
        float a1 = 1.0f - f1*f1;
        float a2 = p2e * (1.0f - f2*f2);
        s2s[wv][sub][j] = s2;
        aps[wv][sub][j] = make_float2(a1, a2);
    }
    __syncthreads();

    // ---- stage 1b: f3, f4, e4, t1, b1, b2 ----
    if (act){
        float acc3 = 0.f, acc4 = 0.f;
        #pragma unroll
        for (int m = 0; m < HB; m++){
            float2 w = w34[j*21+m];
            float  s = s2s[wv][sub][m];
            acc3 = fmaf(s, w.x, acc3);
            acc4 = fmaf(s, w.y, acc4);
        }
        float f3 = fast_tanh(acc3);
        float f4 = fast_tanh(acc4);
        e4 = __expf(f4);
        float p1  = xs[wv][sub][j];
        float s1e = p1 * e4;
        t1 = s1e + f3;
        float b1 = 1.0f - f3*f3;
        float b2 = s1e * (1.0f - f4*f4);
        bps[wv][sub][j] = make_float2(b1, b2);
    }
    __syncthreads();

    if (!valid) return;

    // ---- out vector ----
    dout[b*DD + j]      = t1;
    dout[b*DD + HB + j] = s2;

    // ---- J21 column j into registers: cj[k] = a1[k]*w1[k][j] + a2[k]*w2[k][j]
    float cj[HB];
    #pragma unroll
    for (int k = 0; k < HB; k++){
        float2 a = aps[wv][sub][k];   // broadcast within batch group
        float2 w = w12[k*21+j];       // column read, stride-1 across lanes
        cj[k] = a.x*w.x + a.y*w.y;
    }

    float* J = dout + (size_t)NB*DD + (size_t)b*(DD*DD);

    // ---- top half: TL[i][j], TR[i][j] ----
    // TL[i][j] = e4[i]*(i==j) + b1[i]*sum_k w3[i,k]*cj[k] + b2[i]*sum_k w4[i,k]*cj[k]
    // w3g/w4g indices are wave-uniform -> scalar loads shared by all 3 batches.
    #pragma unroll 2
    for (int i = 0; i < HB; i++){
        float s3 = 0.f, s4 = 0.f;
        #pragma unroll
        for (int k = 0; k < HB; k++){
            s3 = fmaf(w3g[i*HB+k], cj[k], s3);
            s4 = fmaf(w4g[i*HB+k], cj[k], s4);
        }
        float2 bb = bps[wv][sub][i];  // broadcast
        float2 wc = w34[i*21+j];      // w3[i][j], w4[i][j]
        float tl = bb.x*s3 + bb.y*s4 + ((i == j) ? e4 : 0.0f);
        float tr = (bb.x*wc.x + bb.y*wc.y) * e2;
        J[i*DD + j]      = tl;
        J[i*DD + HB + j] = tr;
    }

    // ---- bottom half: BL[i][j] = J21[i][j] = cj[i]; BR = diag(e2) ----
    #pragma unroll 4
    for (int i = 0; i < HB; i++){
        J[(HB+i)*DD + j]      = cj[i];
        J[(HB+i)*DD + HB + j] = (i == j) ? e2 : 0.0f;
    }
}

extern "C" void kernel_launch(void* const* d_in, const int* in_sizes, int n_in,
                              void* d_out, int out_size, void* d_ws, size_t ws_size,
                              hipStream_t stream)
{
    const float* src = (const float*)d_in[0];
    const float* w1  = (const float*)d_in[1];
    const float* w2  = (const float*)d_in[2];
    const float* w3  = (const float*)d_in[3];
    const float* w4  = (const float*)d_in[4];
    float* out = (float*)d_out;
    int NB = in_sizes[0] / DD;
    int grid = (NB + BPB - 1) / BPB;
    hipLaunchKernelGGL(ende_kernel, dim3(grid), dim3(256), 0, stream,
                       src, w1, w2, w3, w4, out, NB);
}

// Round 2
// 451.605 us; speedup vs baseline: 1.1355x; 1.1355x over previous
//
#include <hip/hip_runtime.h>

#define HB  20
#define DD  40
#define BPW 3              // batches per wave (3 x 20 lanes = 60 of 64)
#define WAVES 4            // waves per block (256 threads)
#define BPB (BPW*WAVES)    // 12 batches per block
#define QROWS 10           // J rows per emission quarter
#define QF (QROWS*DD)      // 400 floats per batch-quarter
#define TILE_F (BPW*QF)    // 1200 floats per wave tile

__device__ __forceinline__ float fast_tanh(float x){
    // tanh(x) = 1 - 2/(exp(2x)+1); exact at +-inf, ~1e-7 rel error
    float e = __expf(2.0f*x);
    return 1.0f - 2.0f*__builtin_amdgcn_rcpf(e + 1.0f);
}

__global__ __launch_bounds__(256, 4)
void ende_kernel(const float* __restrict__ src,
                 const float* __restrict__ w1,
                 const float* __restrict__ w2,
                 const float* __restrict__ w3g,
                 const float* __restrict__ w4g,
                 float* __restrict__ dout,
                 int NB)
{
    __shared__ float2 w12[HB*21];            // (w1,w2) row-padded
    __shared__ float2 w34[HB*21];            // (w3,w4) row-padded
    __shared__ float  xs [WAVES][BPW][DD];
    __shared__ float  s2s[WAVES][BPW][HB];
    __shared__ float2 aps[WAVES][BPW][HB];   // (a1,a2)
    __shared__ float2 bps[WAVES][BPW][HB];   // (b1,b2)
    __shared__ __align__(16) float tile[WAVES][TILE_F];  // J staging, per wave

    const int t    = threadIdx.x;
    const int wv   = t >> 6;
    const int lane = t & 63;
    const bool act = lane < (BPW*HB);
    const int sub  = lane / HB;          // batch within wave
    const int j    = lane % HB;          // owned column
    const int batch0 = blockIdx.x * BPB + wv * BPW;
    const int b    = batch0 + sub;
    const bool valid = act && (b < NB);

    // ---- emission lane map: v = lane + 64*it -> (batch sub, float4 offset) ----
    int esub[5], eoff[5];
    #pragma unroll
    for (int it = 0; it < 5; it++){
        int v = lane + 64*it;
        int se = v / 100;                 // 300 float4 per quarter-phase
        esub[it] = se;
        eoff[it] = (v - se*100) * 4;      // float offset within 400-float block
    }

    // ---- stage weights (block-wide) ----
    for (int q = t; q < HB*HB; q += 256){
        int i = q / HB, m = q - i*HB;
        w12[i*21+m] = make_float2(w1[q],  w2[q]);
        w34[i*21+m] = make_float2(w3g[q], w4g[q]);
    }
    // ---- stage x for this wave's batches ----
    {
        int base = batch0 * DD, lim = NB * DD;
        for (int l = lane; l < BPW*DD; l += 64){
            int g = base + l;
            if (g < lim) (&xs[wv][0][0])[l] = src[g];
        }
    }
    __syncthreads();

    float e2 = 0.f, s2 = 0.f, e4 = 0.f, t1 = 0.f;

    // ---- stage 1a: f1,f2,e2,s2,(a1,a2) ----
    if (act){
        float acc1 = 0.f, acc2 = 0.f;
        #pragma unroll
        for (int m = 0; m < HB; m++){
            float2 w = w12[j*21+m];
            float  p = xs[wv][sub][m];
            acc1 = fmaf(p, w.x, acc1);
            acc2 = fmaf(p, w.y, acc2);
        }
        float f1 = fast_tanh(acc1);
        float f2 = fast_tanh(acc2);
        e2 = __expf(f2);
        float p2  = xs[wv][sub][HB+j];
        float p2e = p2 * e2;
        s2 = p2e + f1;
        s2s[wv][sub][j] = s2;
        aps[wv][sub][j] = make_float2(1.0f - f1*f1, p2e*(1.0f - f2*f2));
    }
    __syncthreads();

    // ---- stage 1b: f3,f4,e4,t1,(b1,b2) ----
    if (act){
        float acc3 = 0.f, acc4 = 0.f;
        #pragma unroll
        for (int m = 0; m < HB; m++){
            float2 w = w34[j*21+m];
            float  s = s2s[wv][sub][m];
            acc3 = fmaf(s, w.x, acc3);
            acc4 = fmaf(s, w.y, acc4);
        }
        float f3 = fast_tanh(acc3);
        float f4 = fast_tanh(acc4);
        e4 = __expf(f4);
        float p1  = xs[wv][sub][j];
        float s1e = p1 * e4;
        t1 = s1e + f3;
        bps[wv][sub][j] = make_float2(1.0f - f3*f3, s1e*(1.0f - f4*f4));
    }

    // ---- J21 column j (aps was synced before stage 1b; not rewritten) ----
    float cj[HB];
    if (act){
        #pragma unroll
        for (int k = 0; k < HB; k++){
            float2 a = aps[wv][sub][k];
            float2 w = w12[k*21+j];
            cj[k] = a.x*w.x + a.y*w.y;
        }
    }

    // ---- out vector (tiny, leave scalar) ----
    if (valid){
        dout[b*DD + j]      = t1;
        dout[b*DD + HB + j] = s2;
    }
    __syncthreads();   // bps visible

    float* __restrict__ Jq = dout + (size_t)NB*DD + (size_t)batch0*(DD*DD);

    // ---- quarters 0,1: TL/TR rows ----
    #pragma unroll
    for (int q = 0; q < 2; q++){
        if (valid){
            #pragma unroll
            for (int r = 0; r < QROWS; r++){
                int i = q*QROWS + r;
                float s3 = 0.f, s4 = 0.f;
                #pragma unroll
                for (int k = 0; k < HB; k++){
                    s3 = fmaf(w3g[i*HB+k], cj[k], s3);   // wave-uniform -> s_load
                    s4 = fmaf(w4g[i*HB+k], cj[k], s4);
                }
                float2 bb = bps[wv][sub][i];
                float2 wc = w34[i*21+j];
                float tl = bb.x*s3 + bb.y*s4 + ((i == j) ? e4 : 0.0f);
                float tr = (bb.x*wc.x + bb.y*wc.y) * e2;
                tile[wv][sub*QF + r*DD + j]      = tl;
                tile[wv][sub*QF + r*DD + HB + j] = tr;
            }
        }
        __syncthreads();
        #pragma unroll
        for (int it = 0; it < 5; it++){
            int v  = lane + 64*it;
            int se = esub[it];
            if (v < 300 && (batch0 + se) < NB){
                float4 val = *(const float4*)&tile[wv][se*QF + eoff[it]];
                *(float4*)&Jq[(size_t)se*(DD*DD) + q*QF + eoff[it]] = val;
            }
        }
        __syncthreads();
    }

    // ---- quarters 2,3: BL/BR rows (no compute: cj + diag) ----
    #pragma unroll
    for (int q = 2; q < 4; q++){
        if (valid){
            #pragma unroll
            for (int r = 0; r < QROWS; r++){
                int rr = (q-2)*QROWS + r;
                tile[wv][sub*QF + r*DD + j]      = cj[rr];
                tile[wv][sub*QF + r*DD + HB + j] = (rr == j) ? e2 : 0.0f;
            }
        }
        __syncthreads();
        #pragma unroll
        for (int it = 0; it < 5; it++){
            int v  = lane + 64*it;
            int se = esub[it];
            if (v < 300 && (batch0 + se) < NB){
                float4 val = *(const float4*)&tile[wv][se*QF + eoff[it]];
                *(float4*)&Jq[(size_t)se*(DD*DD) + q*QF + eoff[it]] = val;
            }
        }
        __syncthreads();
    }
}

extern "C" void kernel_launch(void* const* d_in, const int* in_sizes, int n_in,
                              void* d_out, int out_size, void* d_ws, size_t ws_size,
                              hipStream_t stream)
{
    const float* src = (const float*)d_in[0];
    const float* w1  = (const float*)d_in[1];
    const float* w2  = (const float*)d_in[2];
    const float* w3  = (const float*)d_in[3];
    const float* w4  = (const float*)d_in[4];
    float* out = (float*)d_out;
    int NB = in_sizes[0] / DD;
    int grid = (NB + BPB - 1) / BPB;
    hipLaunchKernelGGL(ende_kernel, dim3(grid), dim3(256), 0, stream,
                       src, w1, w2, w3, w4, out, NB);
}